// Round 3
// baseline (771.604 us; speedup 1.0000x reference)
//
#include <hip/hip_runtime.h>

#define N_   64
#define C4_  64
#define V_   25
#define T_   128
#define K_   3
#define OC_  192   // C4_*K_

// ---------------- K1: acc + depthwise temporal conv (5-tap, same pad) -------
// Thread owns t-segments {4j..4j+3, 64+4j..64+4j+3}; halos via overlapping b64
// loads (no LDS, no shfl) -> 12 independent loads in flight per thread.
// 16 rows/block, XCD swizzle keeps batch n on XCD n%8 (matches k23).
__global__ __launch_bounds__(256)
void k1_acc_conv(const float* __restrict__ x, const float* __restrict__ out,
                 const float* __restrict__ conv_w, const float* __restrict__ conv_b,
                 float* __restrict__ s, int branch) {
    int bid  = blockIdx.x;            // 6400 = 8 XCD * 8 n * 100
    int e    = bid & 7;
    int slot = bid >> 3;              // 0..799
    int n    = e + 8 * (slot / 100);
    int inner = slot % 100;           // 100 blocks per n, 16 rows each
    int tid = threadIdx.x;
    int j   = tid & 15;               // t-segment index
    int rl  = tid >> 4;               // row within block
    int rowv = inner * 16 + rl;       // c*25 + v, 0..1599
    int c = rowv / 25, v = rowv - c * 25;

    const float* xrow = x + ((size_t)(n * 256 + branch * C4_ + c) * V_ + v) * T_;
    int ta = j * 4, tb = 64 + j * 4;
    float2 zz; zz.x = 0.f; zz.y = 0.f;
    float4 m0 = *(const float4*)(xrow + ta);
    float4 m1 = *(const float4*)(xrow + tb);
    float2 l0 = j        ? *(const float2*)(xrow + ta - 2) : zz;
    float2 r0 =            *(const float2*)(xrow + ta + 4);
    float2 l1 =            *(const float2*)(xrow + tb - 2);
    float2 r1 = (j < 15) ? *(const float2*)(xrow + tb + 4) : zz;
    if (branch > 0) {
        const float* zrow = out + ((size_t)(n * 256 + (branch - 1) * C4_ + c) * V_ + v) * T_;
        float4 p0 = *(const float4*)(zrow + ta);
        float4 p1 = *(const float4*)(zrow + tb);
        float2 q0 = j        ? *(const float2*)(zrow + ta - 2) : zz;
        float2 s0 =            *(const float2*)(zrow + ta + 4);
        float2 q1 =            *(const float2*)(zrow + tb - 2);
        float2 s1 = (j < 15) ? *(const float2*)(zrow + tb + 4) : zz;
        m0.x += p0.x; m0.y += p0.y; m0.z += p0.z; m0.w += p0.w;
        m1.x += p1.x; m1.y += p1.y; m1.z += p1.z; m1.w += p1.w;
        l0.x += q0.x; l0.y += q0.y; r0.x += s0.x; r0.y += s0.y;
        l1.x += q1.x; l1.y += q1.y; r1.x += s1.x; r1.y += s1.y;
    }

    const float* wp = conv_w + (branch * C4_ + c) * 5;
    float w0 = wp[0], w1 = wp[1], w2 = wp[2], w3 = wp[3], w4 = wp[4];
    float b0 = conv_b[branch * C4_ + c];

    float4 oa, ob;
    oa.x = b0 + w0*l0.x + w1*l0.y + w2*m0.x + w3*m0.y + w4*m0.z;
    oa.y = b0 + w0*l0.y + w1*m0.x + w2*m0.y + w3*m0.z + w4*m0.w;
    oa.z = b0 + w0*m0.x + w1*m0.y + w2*m0.z + w3*m0.w + w4*r0.x;
    oa.w = b0 + w0*m0.y + w1*m0.z + w2*m0.w + w3*r0.x + w4*r0.y;
    ob.x = b0 + w0*l1.x + w1*l1.y + w2*m1.x + w3*m1.y + w4*m1.z;
    ob.y = b0 + w0*l1.y + w1*m1.x + w2*m1.y + w3*m1.z + w4*m1.w;
    ob.z = b0 + w0*m1.x + w1*m1.y + w2*m1.z + w3*m1.w + w4*r1.x;
    ob.w = b0 + w0*m1.y + w1*m1.z + w2*m1.w + w3*r1.x + w4*r1.y;

    float* srow = s + ((size_t)(n * C4_ + c) * V_ + v) * T_;
    *(float4*)(srow + ta) = oa;
    *(float4*)(srow + tb) = ob;
}

// ---------------- K23: fused per-node 1x1 conv + adjacency + BN + LeakyReLU -
// One wave per output channel c. Lane owns a t-pair. s staged via
// global_load_lds double-buffer. NEW: W preloaded to SGPRs in 16-cin chunks
// (pure s_load_dwordx16 bursts), A staged once into LDS (pure-DS h==1 phase)
// -> no SMEM/DS lgkmcnt mixing inside the hot loops.
__global__ __launch_bounds__(256, 4)
void k23(const float* __restrict__ s, const float* __restrict__ gW,
         const float* __restrict__ A,
         const float* __restrict__ bng, const float* __restrict__ bnb,
         const float* __restrict__ bnm, const float* __restrict__ bnv,
         float* __restrict__ out, int branch) {
    __shared__ float lds[8192];        // 2 x (32 cin x 128 t) = 32 KB
    __shared__ float A_lds[1952];      // 75 rows x stride 26 (8B-aligned rows)
    int bid  = blockIdx.x;
    int e    = bid & 7;                // XCD
    int slot = bid >> 3;               // 0..127
    int n    = e + 8 * (slot >> 4);    // 8 n per XCD
    int cg   = slot & 15;
    int wave = threadIdx.x >> 6;
    int lane = threadIdx.x & 63;
    int c    = __builtin_amdgcn_readfirstlane(cg * 4 + wave);
    int t0   = lane * 2;

    // stage A (once): row = k*25+w, padded stride 26
    for (int i = threadIdx.x; i < 1950; i += 256) {
        int row = i / 26, col = i - row * 26;
        A_lds[i] = (col < 25) ? A[row * 25 + col] : 0.f;
    }

    const float* sbase = s + (size_t)n * (C4_ * V_ * T_);

    float2 acc[V_];
    #pragma unroll
    for (int v = 0; v < V_; ++v) { acc[v].x = 0.f; acc[v].y = 0.f; }

    auto stage = [&](int pp, int dbase) {
        int w_ = pp >> 1, h_ = pp & 1;
        const float* g0 = sbase + (size_t)(h_ * 32) * (V_ * T_) + (size_t)w_ * T_;
        #pragma unroll
        for (int jj = 0; jj < 4; ++jj) {
            int idx4 = (wave * 4 + jj) * 64 + lane;
            int cl = idx4 >> 5, t4 = idx4 & 31;
            const float* gp = g0 + (size_t)cl * (V_ * T_) + t4 * 4;
            __builtin_amdgcn_global_load_lds(
                (const __attribute__((address_space(1))) void*)gp,
                (__attribute__((address_space(3))) void*)&lds[dbase + (wave * 4 + jj) * 256],
                16, 0, 0);
        }
    };

    stage(0, 0);
    __syncthreads();

    float2 y0, y1, y2;
    for (int p = 0; p < 50; ++p) {
        int w_ = p >> 1, h = p & 1;
        int cur = (p & 1) * 4096;
        if (p < 49) stage(p + 1, cur ^ 4096);

        const float* Wb = gW + (((size_t)branch * V_ + w_) * OC_ + c * 3) * C4_ + h * 32;
        const float* bp = lds + cur + t0;
        if (h == 0) { y0.x=y0.y=y1.x=y1.y=y2.x=y2.y=0.f; }
        #pragma unroll
        for (int hb = 0; hb < 2; ++hb) {
            // SGPR preload: 3 x 16 contiguous floats (64B-aligned) -> s_load_dwordx16
            float wa[16], wb[16], wc[16];
            #pragma unroll
            for (int q = 0; q < 16; ++q) {
                wa[q] = Wb[hb * 16 + q];
                wb[q] = Wb[C4_ + hb * 16 + q];
                wc[q] = Wb[2 * C4_ + hb * 16 + q];
            }
            #pragma unroll
            for (int q = 0; q < 16; ++q) {
                float2 sv = *(const float2*)(bp + (hb * 16 + q) * T_);
                y0.x += wa[q] * sv.x; y0.y += wa[q] * sv.y;
                y1.x += wb[q] * sv.x; y1.y += wb[q] * sv.y;
                y2.x += wc[q] * sv.x; y2.y += wc[q] * sv.y;
            }
        }
        if (h == 1) {
            const float* A0l = A_lds + (0 * V_ + w_) * 26;
            const float* A1l = A_lds + (1 * V_ + w_) * 26;
            const float* A2l = A_lds + (2 * V_ + w_) * 26;
            #pragma unroll
            for (int vq = 0; vq < 12; ++vq) {
                float2 a0 = *(const float2*)(A0l + 2 * vq);
                float2 a1 = *(const float2*)(A1l + 2 * vq);
                float2 a2 = *(const float2*)(A2l + 2 * vq);
                acc[2*vq].x   += a0.x * y0.x + a1.x * y1.x + a2.x * y2.x;
                acc[2*vq].y   += a0.x * y0.y + a1.x * y1.y + a2.x * y2.y;
                acc[2*vq+1].x += a0.y * y0.x + a1.y * y1.x + a2.y * y2.x;
                acc[2*vq+1].y += a0.y * y0.y + a1.y * y1.y + a2.y * y2.y;
            }
            float a0t = A0l[24], a1t = A1l[24], a2t = A2l[24];
            acc[24].x += a0t * y0.x + a1t * y1.x + a2t * y2.x;
            acc[24].y += a0t * y0.y + a1t * y1.y + a2t * y2.y;
        }
        __syncthreads();
    }

    float g  = bng[branch * C4_ + c];
    float be = bnb[branch * C4_ + c];
    float mu = bnm[branch * C4_ + c];
    float va = bnv[branch * C4_ + c];
    float sc = g * rsqrtf(va + 1e-5f);
    float* op = out + ((size_t)(n * 256 + branch * C4_ + c) * V_) * T_ + t0;
    #pragma unroll
    for (int v = 0; v < V_; ++v) {
        float zx = (acc[v].x - mu) * sc + be;
        float zy = (acc[v].y - mu) * sc + be;
        zx = zx > 0.f ? zx : 0.2f * zx;
        zy = zy > 0.f ? zy : 0.2f * zy;
        float2 o2; o2.x = zx; o2.y = zy;
        *(float2*)(op + (size_t)v * T_) = o2;
    }
}

// ---------------- K4: passthrough split[3] -> out channels 192..255 ---------
__global__ __launch_bounds__(256)
void k4_copy(const float* __restrict__ x, float* __restrict__ out) {
    int i = blockIdx.x * blockDim.x + threadIdx.x;   // 0 .. 3,276,799
    int n = i / 51200;
    int j = i % 51200;
    const float4* src = (const float4*)(x + (size_t)(n * 256 + 192) * (V_ * T_));
    float4* dst = (float4*)(out + (size_t)(n * 256 + 192) * (V_ * T_));
    dst[j] = src[j];
}

extern "C" void kernel_launch(void* const* d_in, const int* in_sizes, int n_in,
                              void* d_out, int out_size, void* d_ws, size_t ws_size,
                              hipStream_t stream) {
    const float* x      = (const float*)d_in[0];
    const float* A      = (const float*)d_in[1];
    const float* conv_w = (const float*)d_in[2];
    const float* conv_b = (const float*)d_in[3];
    const float* gW     = (const float*)d_in[4];
    const float* bng    = (const float*)d_in[5];
    const float* bnb    = (const float*)d_in[6];
    const float* bnm    = (const float*)d_in[7];
    const float* bnv    = (const float*)d_in[8];
    float* out = (float*)d_out;

    float* s = (float*)d_ws;   // N*C4*V*T fp32 = 52,428,800 B

    for (int i = 0; i < 3; ++i) {
        hipLaunchKernelGGL(k1_acc_conv, dim3(6400), dim3(256), 0, stream,
                           x, out, conv_w, conv_b, s, i);
        hipLaunchKernelGGL(k23, dim3(N_ * 16), dim3(256), 0, stream,
                           s, gW, A, bng, bnb, bnm, bnv, out, i);
    }
    hipLaunchKernelGGL(k4_copy, dim3(12800), dim3(256), 0, stream, x, out);
}